// Round 11
// baseline (145.857 us; speedup 1.0000x reference)
//
#include <hip/hip_runtime.h>
#include <hip/hip_bf16.h>
#include <math.h>

#define HDIM 768
#define DD 64
#define SEQL 1024
#define NH 12
#define NB 8

typedef float f32x4 __attribute__((ext_vector_type(4)));
typedef short bf16x8 __attribute__((ext_vector_type(8)));

// ---------------- Kernel 1: seq = hidden@W1+b1, RoPE(q,k)->bf16, bias = seq@W2+b2 (h-major) ----
__global__ __launch_bounds__(128) void k1_seq_rope_bias(
    const float* __restrict__ hidden, const float* __restrict__ W1,
    const float* __restrict__ b1, const float* __restrict__ W2,
    const float* __restrict__ b2,
    __hip_bfloat16* __restrict__ qo, __hip_bfloat16* __restrict__ ko,
    float* __restrict__ bqT, float* __restrict__ bkT)
{
    __shared__ float hs[16 * HDIM];   // 48 KB: 16 hidden rows
    __shared__ float sq[16][132];     // seq tile (pad 132 for banks)
    const int tid = threadIdx.x;
    const long row0 = (long)blockIdx.x * 16;

    const float4* src = (const float4*)(hidden + row0 * HDIM);
    float4* hdst = (float4*)hs;
    #pragma unroll
    for (int t = 0; t < 24; ++t)
        hdst[tid + t * 128] = src[tid + t * 128];
    __syncthreads();

    const int cx = tid & 31;
    const int ry = tid >> 5;
    const float4 bias1 = ((const float4*)b1)[cx];
    float4 acc[4];
    #pragma unroll
    for (int r = 0; r < 4; ++r) acc[r] = bias1;

    for (int k4 = 0; k4 < HDIM / 4; ++k4) {
        float4 w[4];
        #pragma unroll
        for (int kk = 0; kk < 4; ++kk)
            w[kk] = *(const float4*)(W1 + (k4 * 4 + kk) * 128 + cx * 4);
        #pragma unroll
        for (int r = 0; r < 4; ++r) {
            float4 hv = *(const float4*)(hs + (ry * 4 + r) * HDIM + k4 * 4);
            acc[r].x = fmaf(hv.x, w[0].x, fmaf(hv.y, w[1].x, fmaf(hv.z, w[2].x, fmaf(hv.w, w[3].x, acc[r].x))));
            acc[r].y = fmaf(hv.x, w[0].y, fmaf(hv.y, w[1].y, fmaf(hv.z, w[2].y, fmaf(hv.w, w[3].y, acc[r].y))));
            acc[r].z = fmaf(hv.x, w[0].z, fmaf(hv.y, w[1].z, fmaf(hv.z, w[2].z, fmaf(hv.w, w[3].z, acc[r].z))));
            acc[r].w = fmaf(hv.x, w[0].w, fmaf(hv.y, w[1].w, fmaf(hv.z, w[2].w, fmaf(hv.w, w[3].w, acc[r].w))));
        }
    }
    #pragma unroll
    for (int r = 0; r < 4; ++r)
        *(float4*)&sq[ry * 4 + r][cx * 4] = acc[r];
    __syncthreads();

    // bias: 16 rows x 24 outputs, dot over 128; h-major output [h][8192]
    for (int idx = tid; idx < 16 * 24; idx += 128) {
        int r = idx / 24, jj = idx - r * 24;
        float s = b2[jj];
        #pragma unroll 16
        for (int c = 0; c < 128; ++c)
            s = fmaf(sq[r][c], W2[c * 24 + jj], s);
        long grow = row0 + r;
        if (jj & 1) bkT[(long)(jj >> 1) * (NB * SEQL) + grow] = s;
        else        bqT[(long)(jj >> 1) * (NB * SEQL) + grow] = s;
    }

    // RoPE: 16 rows x 32 pairs, q and k share sincos; bf16 outputs
    for (int idx = tid; idx < 16 * 32; idx += 128) {
        int r = idx >> 5, p = idx & 31;
        long grow = row0 + r;
        int pos = (int)(grow & (SEQL - 1));
        float inv = __expf((float)p * -0.28782313662425576f); // 10000^(-p/32)
        float ang = (float)pos * inv;
        float sn, cs;
        __sincosf(ang, &sn, &cs);
        long base = grow * DD;
        float x0 = sq[r][2 * p], x1 = sq[r][2 * p + 1];
        qo[base + 2 * p]     = __float2bfloat16(x0 * cs - x1 * sn);
        qo[base + 2 * p + 1] = __float2bfloat16(x1 * cs + x0 * sn);
        float y0 = sq[r][DD + 2 * p], y1 = sq[r][DD + 2 * p + 1];
        ko[base + 2 * p]     = __float2bfloat16(y0 * cs - y1 * sn);
        ko[base + 2 * p + 1] = __float2bfloat16(y1 * cs + y0 * sn);
    }
}

// ---------------- Kernel 2: block = (b, h, 32-row m-band) -> one CONTIGUOUS 128 KB output slab --
// 3072 blocks x 256 threads (4 waves). qk recomputed per head via bf16 MFMA (cheap on matrix pipe);
// wave wv owns cols [wv*256, wv*256+256). Frag layouts (m89/m92-verified):
//   A (16x32): row = lane&15, k = (lane>>4)*8 + i   (q rows, 8 contiguous bf16 = 16B/lane)
//   B (16x32): col = lane&15, k = (lane>>4)*8 + i   (k^T rows, same pattern, direct from L2)
//   C/D:       col = lane&15, row = (lane>>4)*4 + j
// Mask folded into bias staging (-inf poison) -> no per-element mask ops. Epilogue: 2 LDS-transpose
// passes of 16 rows, then NT f4 stores; per store instruction each wave writes 1 KB contiguous and
// the block emits one linear 128 KB stream; consecutive blockIdx = consecutive slabs.
__global__ __launch_bounds__(256) void k2_mfma(
    const __hip_bfloat16* __restrict__ qb, const __hip_bfloat16* __restrict__ kb,
    const float* __restrict__ bqT, const float* __restrict__ bkT,
    const int* __restrict__ mask, float* __restrict__ out)
{
    __shared__ float tbuf[16][1028];  // 65.8 KB transpose buffer (pad: 2-way max on writes)
    __shared__ float bks[SEQL];      // 4 KB, mask-poisoned bk for this (b,h)
    __shared__ float bqs[32];        // mask-poisoned bq for this band
    const int tid = threadIdx.x;
    const int lane = tid & 63;
    const int wv = tid >> 6;
    const int bid = blockIdx.x;
    const int mband = bid & 31;
    const int h = (bid >> 5) % NH;
    const int b = bid / (NH * 32);
    const int m0 = mband * 32;

    // stage bk[1024] + bq[32], poisoned to -inf where mask==0
    {
        float4 v = ((const float4*)(bkT + (long)h * (NB * SEQL) + b * SEQL))[tid];
        int4 mk = ((const int4*)(mask + b * SEQL))[tid];
        float4 o;
        o.x = mk.x ? v.x : -INFINITY;
        o.y = mk.y ? v.y : -INFINITY;
        o.z = mk.z ? v.z : -INFINITY;
        o.w = mk.w ? v.w : -INFINITY;
        ((float4*)bks)[tid] = o;
    }
    if (tid < 32) {
        float v = bqT[(long)h * (NB * SEQL) + b * SEQL + m0 + tid];
        bqs[tid] = mask[b * SEQL + m0 + tid] ? v : -INFINITY;
    }

    // A-frags: q rows m0..m0+31, 2 m-tiles x 2 K-halves
    const __hip_bfloat16* qrow = qb + ((long)b * SEQL + m0 + (lane & 15)) * DD + (lane >> 4) * 8;
    bf16x8 afrag[2][2];
    #pragma unroll
    for (int mt = 0; mt < 2; ++mt)
        #pragma unroll
        for (int hf = 0; hf < 2; ++hf)
            afrag[mt][hf] = *(const bf16x8*)(qrow + mt * 16 * DD + hf * 32);

    f32x4 acc[2][16];
    #pragma unroll
    for (int mt = 0; mt < 2; ++mt)
        #pragma unroll
        for (int ns = 0; ns < 16; ++ns) acc[mt][ns] = 0.f;

    // MFMA loop: 16 n-steps x (2 m-tiles x 2 K-halves) = 64 MFMA/wave
    const __hip_bfloat16* kbase = kb + (long)b * SEQL * DD + ((long)wv * 256 + (lane & 15)) * DD + (lane >> 4) * 8;
    #pragma unroll
    for (int ns = 0; ns < 16; ++ns) {
        const __hip_bfloat16* kr = kbase + ns * 16 * DD;
        bf16x8 b0 = *(const bf16x8*)(kr);
        bf16x8 b1 = *(const bf16x8*)(kr + 32);
        acc[0][ns] = __builtin_amdgcn_mfma_f32_16x16x32_bf16(afrag[0][0], b0, acc[0][ns], 0, 0, 0);
        acc[0][ns] = __builtin_amdgcn_mfma_f32_16x16x32_bf16(afrag[0][1], b1, acc[0][ns], 0, 0, 0);
        acc[1][ns] = __builtin_amdgcn_mfma_f32_16x16x32_bf16(afrag[1][0], b0, acc[1][ns], 0, 0, 0);
        acc[1][ns] = __builtin_amdgcn_mfma_f32_16x16x32_bf16(afrag[1][1], b1, acc[1][ns], 0, 0, 0);
    }
    __syncthreads();  // bks/bqs staged; tbuf about to be used

    // fold + 2 transpose/store passes of 16 rows each
    #pragma unroll
    for (int mt = 0; mt < 2; ++mt) {
        #pragma unroll
        for (int ns = 0; ns < 16; ++ns) {
            const int ncol = wv * 256 + ns * 16 + (lane & 15);
            const float bkv = bks[ncol];
            #pragma unroll
            for (int j = 0; j < 4; ++j) {
                const int lr = (lane >> 4) * 4 + j;          // local row in m-tile
                float v = acc[mt][ns][j] * 0.125f + bqs[mt * 16 + lr] + bkv;
                if (m0 + mt * 16 + lr > ncol) v -= 1e12f;    // causal tri
                tbuf[lr][ncol] = v;
            }
        }
        __syncthreads();
        float* ob = out + ((long)(b * NH + h) << 20) + ((long)(m0 + mt * 16) << 10);
        #pragma unroll
        for (int it = 0; it < 16; ++it) {
            const int i = tid + it * 256;
            const int r = i >> 8, c4 = i & 255;
            f32x4 v = *(const f32x4*)&tbuf[r][c4 * 4];
            __builtin_nontemporal_store(v, (f32x4*)(ob + ((long)r << 10) + c4 * 4));
        }
        __syncthreads();
    }
}

extern "C" void kernel_launch(void* const* d_in, const int* in_sizes, int n_in,
                              void* d_out, int out_size, void* d_ws, size_t ws_size,
                              hipStream_t stream) {
    const float* hidden = (const float*)d_in[0];
    const int*   mask   = (const int*)d_in[1];
    const float* W1     = (const float*)d_in[2];
    const float* b1     = (const float*)d_in[3];
    const float* W2     = (const float*)d_in[4];
    const float* b2     = (const float*)d_in[5];
    float* out = (float*)d_out;

    char* ws = (char*)d_ws;
    __hip_bfloat16* qbuf = (__hip_bfloat16*)ws;                       // 8192*64 bf16 = 1 MB
    __hip_bfloat16* kbuf = (__hip_bfloat16*)(ws + (1 << 20));         // 1 MB
    float* bqT = (float*)(ws + (2 << 20));                            // [12][8192] = 384 KB
    float* bkT = (float*)(ws + (2 << 20) + 384 * 1024);               // [12][8192]

    k1_seq_rope_bias<<<512, 128, 0, stream>>>(hidden, W1, b1, W2, b2,
                                              qbuf, kbuf, bqT, bkT);
    k2_mfma<<<NB * NH * 32, 256, 0, stream>>>(qbuf, kbuf, bqT, bkT, mask, out);
}